// Round 17
// baseline (1074.616 us; speedup 1.0000x reference)
//
#include <hip/hip_runtime.h>

#define DIMN 8192
#define SEQ  1024
#define NHEAD 128

typedef __attribute__((ext_vector_type(8))) short bf16x8;
typedef __attribute__((ext_vector_type(4))) float f32x4;

#define MFMA16(a, b, c) __builtin_amdgcn_mfma_f32_16x16x32_bf16((a), (b), (c), 0, 0, 0)

__device__ __forceinline__ unsigned short f2bf(float f) {
  unsigned u = __float_as_uint(f);
  return (unsigned short)((u + 0x7FFFu + ((u >> 16) & 1u)) >> 16);
}
__device__ __forceinline__ unsigned pack2(float a, float b) {
  return (unsigned)f2bf(a) | ((unsigned)f2bf(b) << 16);
}
__device__ __forceinline__ unsigned pack2_rhu(float lo, float hi) {
  unsigned a = __float_as_uint(lo) + 0x8000u;
  unsigned b = __float_as_uint(hi) + 0x8000u;
  return (a >> 16) | (b & 0xFFFF0000u);
}
__device__ __forceinline__ unsigned short f2bf_rhu(float f) {
  return (unsigned short)((__float_as_uint(f) + 0x8000u) >> 16);
}
__device__ __forceinline__ void async_copy16(void* lds_dst, const void* gsrc) {
  __builtin_amdgcn_global_load_lds(
      (const __attribute__((address_space(1))) unsigned int*)gsrc,
      (__attribute__((address_space(3))) unsigned int*)lds_dst, 16, 0, 0);
}

// ---------------- shared device bodies ----------------

__device__ __forceinline__ void cvt_body(int i, const float* __restrict__ in,
                                         unsigned short* __restrict__ out) {
  const float4* p = (const float4*)in;
  float4 a = p[2 * i];
  float4 b = p[2 * i + 1];
  uint4 r;
  r.x = pack2(a.x, a.y);
  r.y = pack2(a.z, a.w);
  r.z = pack2(b.x, b.y);
  r.w = pack2(b.z, b.w);
  ((uint4*)out)[i] = r;
}

// W[k][n] fp32 -> Wt[n][k] bf16, 64x64 tile (v2: k-major b128 store, read-side
// transpose at 4-way max; verified R14/R16, ~75us/matrix standalone).
__device__ __forceinline__ void transpose_body(unsigned short* T,
                                               const float* __restrict__ W,
                                               unsigned short* __restrict__ Wt,
                                               int tbid, int t) {
  const int k0 = (tbid & 127) * 64;
  const int n0 = (tbid >> 7) * 64;
  const int slot = t & 7;
  const int kr = t >> 3;
#pragma unroll
  for (int pass = 0; pass < 2; ++pass) {
    int k = kr + pass * 32;
    const float* src = &W[(size_t)(k0 + k) * DIMN + n0 + slot * 8];
    float4 a = *(const float4*)src;
    float4 b = *(const float4*)(src + 4);
    uint4 r;
    r.x = pack2_rhu(a.x, a.y);
    r.y = pack2_rhu(a.z, a.w);
    r.z = pack2_rhu(b.x, b.y);
    r.w = pack2_rhu(b.z, b.w);
    *(uint4*)&T[k * 72 + slot * 8] = r;
  }
  __syncthreads();
  const int n = 4 * ((t >> 2) & 15) + (t >> 6);
  const int c = (t & 3) * 16;
  unsigned short tmp[16];
#pragma unroll
  for (int j = 0; j < 16; ++j) tmp[j] = T[(c + j) * 72 + n];
  uint4* dst = (uint4*)&Wt[(size_t)(n0 + n) * DIMN + k0 + c];
  dst[0] = *(uint4*)&tmp[0];
  dst[1] = *(uint4*)&tmp[8];
}

// BK=32 pure-DMA GEMM body: 128x128 tile, 4 waves, 32KB LDS (2x16KB dbuf).
// Geometry = R15's gemm_sk (hardware-verified: absmax pass, 0 bank conflicts)
// WITHOUT split-K: full K=8192 per block (256 tiles), direct output.
template <int WRITE_F32>
__device__ __forceinline__ void gemm32_body(
    unsigned short* smem, const unsigned short* __restrict__ A,
    const unsigned short* __restrict__ Wt, void* __restrict__ Cout,
    float out_scale, int bid, int t) {
  const int l = t & 63;
  const int w = t >> 6;
  const int wm = w >> 1, wn = w & 1;
  const int logical = (bid & 7) * 64 + (bid >> 3);  // XCD swizzle (512 blocks)
  const int m0 = (logical & 7) * 128;
  const int n0 = (logical >> 3) * 128;

  const int drow = l >> 2;
  const int dslot = (l & 3) ^ ((l >> 3) & 3);  // source pre-swizzle

  f32x4 acc[4][4];
#pragma unroll
  for (int mb = 0; mb < 4; ++mb)
#pragma unroll
    for (int nb = 0; nb < 4; ++nb) acc[mb][nb] = (f32x4){0.f, 0.f, 0.f, 0.f};

  const unsigned short* aptr = A  + (size_t)(m0 + w * 32 + drow) * DIMN + dslot * 8;
  const unsigned short* bptr = Wt + (size_t)(n0 + w * 32 + drow) * DIMN + dslot * 8;

  auto stage = [&](int buf) {  // 4 DMA per wave (2 A + 2 B)
    unsigned short* sa = &smem[buf * 8192];
    unsigned short* sb = sa + 4096;
#pragma unroll
    for (int i = 0; i < 2; ++i)
      async_copy16(&sa[(w * 32 + i * 16) * 32], aptr + (size_t)i * 16 * DIMN);
#pragma unroll
    for (int i = 0; i < 2; ++i)
      async_copy16(&sb[(w * 32 + i * 16) * 32], bptr + (size_t)i * 16 * DIMN);
    aptr += 32;
    bptr += 32;
  };
  auto compute = [&](int buf) {  // 8 ds_read_b128 + 16 MFMA per wave
    const unsigned short* la = &smem[buf * 8192];
    const unsigned short* lb = la + 4096;
    bf16x8 af[4], bf[4];
#pragma unroll
    for (int mb = 0; mb < 4; ++mb) {
      int row = wm * 64 + mb * 16 + (l & 15);
      int p = (l >> 4) ^ (((l & 15) >> 1) & 3);
      af[mb] = *(const bf16x8*)&la[row * 32 + p * 8];
    }
#pragma unroll
    for (int nb = 0; nb < 4; ++nb) {
      int row = wn * 64 + nb * 16 + (l & 15);
      int p = (l >> 4) ^ (((l & 15) >> 1) & 3);
      bf[nb] = *(const bf16x8*)&lb[row * 32 + p * 8];
    }
    __builtin_amdgcn_s_setprio(1);
#pragma unroll
    for (int mb = 0; mb < 4; ++mb)
#pragma unroll
      for (int nb = 0; nb < 4; ++nb)
        acc[mb][nb] = MFMA16(af[mb], bf[nb], acc[mb][nb]);
    __builtin_amdgcn_s_setprio(0);
  };

  stage(0);
  __syncthreads();
  int buf = 0;
  for (int kt = 0; kt < 256; ++kt) {
    if (kt < 255) stage(buf ^ 1);
    compute(buf);
    __syncthreads();
    buf ^= 1;
  }

#pragma unroll
  for (int mb = 0; mb < 4; ++mb)
#pragma unroll
    for (int nb = 0; nb < 4; ++nb)
#pragma unroll
      for (int r = 0; r < 4; ++r) {
        int rg = m0 + wm * 64 + mb * 16 + (l >> 4) * 4 + r;
        int cg = n0 + wn * 64 + nb * 16 + (l & 15);
        float vl = acc[mb][nb][r] * out_scale;
        if (WRITE_F32)
          ((float*)Cout)[(size_t)rg * DIMN + cg] = vl;
        else
          ((unsigned short*)Cout)[(size_t)rg * DIMN + cg] = f2bf(vl);
      }
}

// ---------------- standalone kernels (serial fallback paths) ----------------

__global__ __launch_bounds__(256) void cvt_bf16_kernel(
    const float* __restrict__ in, unsigned short* __restrict__ out) {
  cvt_body(blockIdx.x * 256 + threadIdx.x, in, out);
}

__global__ __launch_bounds__(256) void transpose_cvt_kernel(
    const float* __restrict__ W, unsigned short* __restrict__ Wt) {
  __shared__ unsigned short T[64 * 72];
  transpose_body(T, W, Wt, blockIdx.x, threadIdx.x);
}

// ---------------- fused co-scheduled kernels ----------------
// R16 DIAGNOSIS: every piece near its local roofline; remaining waste is the
// SERIALIZATION of compute-bound GEMM (12% HBM) and memory-bound transpose.
// Streams/events are graph-capture-forbidden -> block-level fusion: one launch
// = 512 GEMM blocks (32KB LDS each) + 16384 transpose blocks (9KB, allocated
// 32KB). Per CU: 2 GEMM + 3 transpose = 160KB exact; transpose's 384MB HBM
// flows in the GEMM's shadow. Wt double-buffered (Wt0/Wt1 ping-pong).
__global__ __launch_bounds__(256) void cvtT_kernel(
    const float* __restrict__ x, unsigned short* __restrict__ xb,
    const float* __restrict__ W, unsigned short* __restrict__ Wt) {
  extern __shared__ unsigned short dynsm[];
  if (blockIdx.x < 4096)
    cvt_body(blockIdx.x * 256 + threadIdx.x, x, xb);
  else
    transpose_body(dynsm, W, Wt, blockIdx.x - 4096, threadIdx.x);
}

template <int WRITE_F32>
__global__ __launch_bounds__(256) void gemmT_kernel(
    const unsigned short* __restrict__ A, const unsigned short* __restrict__ Wtin,
    void* __restrict__ Cout, float out_scale,
    const float* __restrict__ Wnext, unsigned short* __restrict__ Wtout) {
  extern __shared__ unsigned short dynsm[];
  if (blockIdx.x < 512)
    gemm32_body<WRITE_F32>(dynsm, A, Wtin, Cout, out_scale, blockIdx.x, threadIdx.x);
  else
    transpose_body(dynsm, Wnext, Wtout, blockIdx.x - 512, threadIdx.x);
}

// ---------------- pure-DMA BK=64 GEMM (R14 verified; serial middle path) ----
template <int WRITE_F32>
__global__ __launch_bounds__(256, 2) void gemm_dma(
    const unsigned short* __restrict__ A, const unsigned short* __restrict__ Wt,
    void* __restrict__ Cout, float out_scale) {
  __shared__ unsigned short smem[2 * 16384];
  const int t = threadIdx.x;
  const int l = t & 63;
  const int w = t >> 6;
  const int wm = w >> 1, wn = w & 1;
  const int logical = (blockIdx.x & 7) * 64 + (blockIdx.x >> 3);
  const int m0 = (logical & 7) * 128;
  const int n0 = (logical >> 3) * 128;
  const int rin = l >> 3;
  const int aslot = (l & 7) ^ rin;

  f32x4 acc[4][4];
#pragma unroll
  for (int mb = 0; mb < 4; ++mb)
#pragma unroll
    for (int nb = 0; nb < 4; ++nb) acc[mb][nb] = (f32x4){0.f, 0.f, 0.f, 0.f};

  const unsigned short* aptr = A  + (size_t)(m0 + w * 32 + rin) * DIMN + aslot * 8;
  const unsigned short* bptr = Wt + (size_t)(n0 + w * 32 + rin) * DIMN + aslot * 8;

  auto stage = [&](int buf) {
    unsigned short* sa = &smem[buf * 16384];
    unsigned short* sb = sa + 8192;
#pragma unroll
    for (int i = 0; i < 4; ++i)
      async_copy16(&sa[(w * 32 + i * 8) * 64], aptr + (size_t)i * 8 * DIMN);
#pragma unroll
    for (int i = 0; i < 4; ++i)
      async_copy16(&sb[(w * 32 + i * 8) * 64], bptr + (size_t)i * 8 * DIMN);
    aptr += 64;
    bptr += 64;
  };
  auto compute = [&](int buf) {
    const unsigned short* la = &smem[buf * 16384];
    const unsigned short* lb = la + 8192;
#pragma unroll
    for (int kh = 0; kh < 2; ++kh) {
      bf16x8 af[4], bf[4];
#pragma unroll
      for (int mb = 0; mb < 4; ++mb) {
        int row = wm * 64 + mb * 16 + (l & 15);
        int sl = ((l >> 4) + kh * 4) ^ (row & 7);
        af[mb] = *(const bf16x8*)&la[row * 64 + sl * 8];
      }
#pragma unroll
      for (int nb = 0; nb < 4; ++nb) {
        int row = wn * 64 + nb * 16 + (l & 15);
        int sl = ((l >> 4) + kh * 4) ^ (row & 7);
        bf[nb] = *(const bf16x8*)&lb[row * 64 + sl * 8];
      }
      __builtin_amdgcn_s_setprio(1);
#pragma unroll
      for (int mb = 0; mb < 4; ++mb)
#pragma unroll
        for (int nb = 0; nb < 4; ++nb)
          acc[mb][nb] = MFMA16(af[mb], bf[nb], acc[mb][nb]);
      __builtin_amdgcn_s_setprio(0);
    }
  };

  stage(0);
  __syncthreads();
  int buf = 0;
  for (int kt = 0; kt < 128; ++kt) {
    if (kt < 127) stage(buf ^ 1);
    compute(buf);
    __syncthreads();
    buf ^= 1;
  }

#pragma unroll
  for (int mb = 0; mb < 4; ++mb)
#pragma unroll
    for (int nb = 0; nb < 4; ++nb)
#pragma unroll
      for (int r = 0; r < 4; ++r) {
        int rg = m0 + wm * 64 + mb * 16 + (l >> 4) * 4 + r;
        int cg = n0 + wn * 64 + nb * 16 + (l & 15);
        float vl = acc[mb][nb][r] * out_scale;
        if (WRITE_F32)
          ((float*)Cout)[(size_t)rg * DIMN + cg] = vl;
        else
          ((unsigned short*)Cout)[(size_t)rg * DIMN + cg] = f2bf(vl);
      }
}

// ---------------- fallback GEMM (R11 reg-staging) — ws too small for Wt ----
template <int WRITE_F32>
__global__ __launch_bounds__(256, 3) void gemm_fb(
    const unsigned short* __restrict__ A, const float* __restrict__ W,
    void* __restrict__ Cout, float out_scale) {
  __shared__ unsigned short smem[2 * 8192];
  const int t = threadIdx.x;
  const int l = t & 63;
  const int w = t >> 6;
  const int wm = w >> 1, wn = w & 1;
  const int logical = (blockIdx.x & 7) * 64 + (blockIdx.x >> 3);
  const int m0 = (logical & 7) * 128;
  const int n0 = (logical >> 3) * 128;
  const int arow = l >> 2;
  const int aslot = l & 3;
  const int bn = t & 127;
  const int bkb = (t >> 7) * 16;

  f32x4 acc[4][4];
#pragma unroll
  for (int mb = 0; mb < 4; ++mb)
#pragma unroll
    for (int nb = 0; nb < 4; ++nb) acc[mb][nb] = (f32x4){0.f, 0.f, 0.f, 0.f};

  float fb[16];
  const unsigned short* aptr = A + (size_t)(m0 + w * 32 + arow) * DIMN + aslot * 8;
  const float* wp = W + (size_t)bkb * DIMN + n0 + bn;

  auto load_B = [&]() {
#pragma unroll
    for (int i = 0; i < 16; ++i) fb[i] = wp[(size_t)i * DIMN];
    wp += (size_t)32 * DIMN;
  };
  auto write_B = [&](int buf) {
    unsigned short* bb = &smem[buf * 8192 + 4096];
    const int ps = (bn >> 1) & 3;
#pragma unroll
    for (int j = 0; j < 2; ++j) {
      int p = ((bkb >> 3) + j) ^ ps;
      uint4 val;
      val.x = pack2_rhu(fb[j * 8 + 0], fb[j * 8 + 1]);
      val.y = pack2_rhu(fb[j * 8 + 2], fb[j * 8 + 3]);
      val.z = pack2_rhu(fb[j * 8 + 4], fb[j * 8 + 5]);
      val.w = pack2_rhu(fb[j * 8 + 6], fb[j * 8 + 7]);
      *(uint4*)&bb[bn * 32 + p * 8] = val;
    }
  };
  auto stage_A = [&](int buf) {
#pragma unroll
    for (int i = 0; i < 2; ++i)
      async_copy16(&smem[buf * 8192 + (w * 32 + i * 16) * 32],
                   aptr + (size_t)i * 16 * DIMN);
    aptr += 32;
  };
  auto compute = [&](int buf) {
    const unsigned short* la = &smem[buf * 8192];
    const unsigned short* lb = la + 4096;
    bf16x8 af[4], bf[4];
#pragma unroll
    for (int mb = 0; mb < 4; ++mb) {
      int row = wm * 64 + mb * 16 + (l & 15);
      af[mb] = *(const bf16x8*)&la[row * 32 + (l >> 4) * 8];
    }
#pragma unroll
    for (int nb = 0; nb < 4; ++nb) {
      int row = wn * 64 + nb * 16 + (l & 15);
      int p = (l >> 4) ^ ((row >> 1) & 3);
      bf[nb] = *(const bf16x8*)&lb[row * 32 + p * 8];
    }
#pragma unroll
    for (int mb = 0; mb < 4; ++mb)
#pragma unroll
      for (int nb = 0; nb < 4; ++nb)
        acc[mb][nb] = MFMA16(af[mb], bf[nb], acc[mb][nb]);
  };

  load_B();
  stage_A(0);
  write_B(0);
  __syncthreads();
  int buf = 0;
  for (int kt = 0; kt < 256; ++kt) {
    if (kt < 255) {
      load_B();
      stage_A(buf ^ 1);
    }
    compute(buf);
    if (kt < 255) write_B(buf ^ 1);
    __syncthreads();
    buf ^= 1;
  }
#pragma unroll
  for (int mb = 0; mb < 4; ++mb)
#pragma unroll
    for (int nb = 0; nb < 4; ++nb)
#pragma unroll
      for (int r = 0; r < 4; ++r) {
        int rg = m0 + wm * 64 + mb * 16 + (l >> 4) * 4 + r;
        int cg = n0 + wn * 64 + nb * 16 + (l & 15);
        float vl = acc[mb][nb][r] * out_scale;
        if (WRITE_F32)
          ((float*)Cout)[(size_t)rg * DIMN + cg] = vl;
        else
          ((unsigned short*)Cout)[(size_t)rg * DIMN + cg] = f2bf(vl);
      }
}

// ---------------- fused flash attention v3: QBLK=128 (unchanged) ----------------
__global__ __launch_bounds__(256) void attn_kernel(
    const unsigned short* __restrict__ q, const unsigned short* __restrict__ k,
    const unsigned short* __restrict__ v, unsigned short* __restrict__ o) {
  __shared__ unsigned short Qs[128 * 64];
  __shared__ unsigned short Ks[2][64 * 64];
  __shared__ unsigned short Vt[64 * 72];
  __shared__ unsigned short Ps[4][16 * 72];

  const int t = threadIdx.x, l = t & 63, w = t >> 6;
  const int logical = (blockIdx.x & 7) * 128 + (blockIdx.x >> 3);
  const int h = logical >> 3;
  const int q0 = (logical & 7) * 128;

  const int rin = l >> 3;
  const int aslot = (l & 7) ^ rin;
  const int skey = t >> 2;
  const int sd = (t & 3) * 16;

  const unsigned short* qsrc = q + (size_t)(q0 + w * 32 + rin) * DIMN + h * 64 + aslot * 8;
  const unsigned short* ksrc = k + (size_t)(w * 16 + rin) * DIMN + h * 64 + aslot * 8;
  const unsigned short* vsrc = v + (size_t)skey * DIMN + h * 64 + sd;

  auto kdma = [&](int buf, int kv) {
#pragma unroll
    for (int i = 0; i < 2; ++i)
      async_copy16(&Ks[buf][(w * 16 + i * 8) * 64],
                   ksrc + (size_t)(kv * 64 + i * 8) * DIMN);
  };
  uint4 va0, va1, vb0, vb1;
  auto vload = [&](uint4& r0, uint4& r1, int kv) {
    const unsigned short* p = vsrc + (size_t)(kv * 64) * DIMN;
    r0 = *(const uint4*)p;
    r1 = *(const uint4*)(p + 8);
  };
  auto vwrite = [&](const uint4& r0, const uint4& r1) {
    const unsigned short* cs = (const unsigned short*)&r0;
    const unsigned short* ds = (const unsigned short*)&r1;
#pragma unroll
    for (int j = 0; j < 8; ++j) {
      int row = sd + j;
      Vt[row * 72 + (((skey >> 3) ^ ((row >> 3) & 7)) << 3) + (skey & 7)] = cs[j];
    }
#pragma unroll
    for (int j = 0; j < 8; ++j) {
      int row = sd + 8 + j;
      Vt[row * 72 + (((skey >> 3) ^ ((row >> 3) & 7)) << 3) + (skey & 7)] = ds[j];
    }
  };

  float m_run[2][4], l_run[2][4];
  f32x4 oacc[2][4];
#pragma unroll
  for (int qh = 0; qh < 2; ++qh) {
#pragma unroll
    for (int r = 0; r < 4; ++r) { m_run[qh][r] = -1e30f; l_run[qh][r] = 0.f; }
#pragma unroll
    for (int db = 0; db < 4; ++db) oacc[qh][db] = (f32x4){0.f, 0.f, 0.f, 0.f};
  }

#pragma unroll
  for (int i = 0; i < 4; ++i)
    async_copy16(&Qs[(w * 32 + i * 8) * 64], qsrc + (size_t)(i * 8) * DIMN);
  kdma(0, 0);
  vload(va0, va1, 0);
  __syncthreads();

  bf16x8 qf[2][2];
#pragma unroll
  for (int qh = 0; qh < 2; ++qh)
#pragma unroll
    for (int kh = 0; kh < 2; ++kh) {
      int row = w * 32 + qh * 16 + (l & 15);
      int s = (l >> 4) + kh * 4;
      qf[qh][kh] = *(const bf16x8*)&Qs[row * 64 + (s ^ (row & 7)) * 8];
    }

  auto compute = [&](int kbuf) {
#pragma unroll
    for (int qh = 0; qh < 2; ++qh) {
      f32x4 sAcc[4];
#pragma unroll
      for (int nb = 0; nb < 4; ++nb) sAcc[nb] = (f32x4){0.f, 0.f, 0.f, 0.f};
#pragma unroll
      for (int kh = 0; kh < 2; ++kh) {
        bf16x8 kf[4];
#pragma unroll
        for (int nb = 0; nb < 4; ++nb) {
          int row = nb * 16 + (l & 15);
          int s = (l >> 4) + kh * 4;
          kf[nb] = *(const bf16x8*)&Ks[kbuf][row * 64 + (s ^ (row & 7)) * 8];
        }
        __builtin_amdgcn_s_setprio(1);
#pragma unroll
        for (int nb = 0; nb < 4; ++nb) sAcc[nb] = MFMA16(qf[qh][kh], kf[nb], sAcc[nb]);
        __builtin_amdgcn_s_setprio(0);
      }
      float sc[4], mx[4];
#pragma unroll
      for (int r = 0; r < 4; ++r) {
        float mv = fmaxf(fmaxf(sAcc[0][r], sAcc[1][r]), fmaxf(sAcc[2][r], sAcc[3][r]));
        mv = fmaxf(mv, __shfl_xor(mv, 1));
        mv = fmaxf(mv, __shfl_xor(mv, 2));
        mv = fmaxf(mv, __shfl_xor(mv, 4));
        mv = fmaxf(mv, __shfl_xor(mv, 8));
        float mn = fmaxf(m_run[qh][r], mv);
        sc[r] = __expf(m_run[qh][r] - mn);
        m_run[qh][r] = mn;
        mx[r] = mn;
      }
#pragma unroll
      for (int nb = 0; nb < 4; ++nb) {
        f32x4 sv = sAcc[nb];
#pragma unroll
        for (int r = 0; r < 4; ++r) sv[r] = __expf(sv[r] - mx[r]);
        sAcc[nb] = sv;
      }
#pragma unroll
      for (int r = 0; r < 4; ++r) {
        float ls = sAcc[0][r] + sAcc[1][r] + sAcc[2][r] + sAcc[3][r];
        ls += __shfl_xor(ls, 1);
        ls += __shfl_xor(ls, 2);
        ls += __shfl_xor(ls, 4);
        ls += __shfl_xor(ls, 8);
        l_run[qh][r] = l_run[qh][r] * sc[r] + ls;
      }
#pragma unroll
      for (int db = 0; db < 4; ++db) {
        f32x4 ov = oacc[qh][db];
#pragma unroll
        for (int r = 0; r < 4; ++r) ov[r] *= sc[r];
        oacc[qh][db] = ov;
      }
#pragma unroll
      for (int nb = 0; nb < 4; ++nb)
#pragma unroll
        for (int r = 0; r < 4; ++r)
          Ps[w][((l >> 4) * 4 + r) * 72 + nb * 16 + (l & 15)] = f2bf_rhu(sAcc[nb][r]);
#pragma unroll
      for (int kh = 0; kh < 2; ++kh) {
        bf16x8 pf = *(const bf16x8*)&Ps[w][(l & 15) * 72 + (l >> 4) * 8 + kh * 32];
        bf16x8 vf[4];
#pragma unroll
        for (int db = 0; db < 4; ++db) {
          int R = db * 16 + (l & 15);
          int s = (l >> 4) + kh * 4;
          vf[db] = *(const bf16x8*)&Vt[R * 72 + (s ^ ((R >> 3) & 7)) * 8];
        }
        __builtin_amdgcn_s_setprio(1);
#pragma unroll
        for (int db = 0; db < 4; ++db) oacc[qh][db] = MFMA16(pf, vf[db], oacc[qh][db]);
        __builtin_amdgcn_s_setprio(0);
      }
    }
  };

  for (int it = 0; it < 8; ++it) {
    int t0 = 2 * it;
    vwrite(va0, va1);
    __syncthreads();
    kdma(1, t0 + 1);
    vload(vb0, vb1, t0 + 1);
    compute(0);
    __syncthreads();
    vwrite(vb0, vb1);
    __syncthreads();
    if (it < 7) {
      kdma(0, t0 + 2);
      vload(va0, va1, t0 + 2);
    }
    compute(1);
    __syncthreads();
  }

#pragma unroll
  for (int qh = 0; qh < 2; ++qh)
#pragma unroll
    for (int db = 0; db < 4; ++db)
#pragma unroll
      for (int r = 0; r < 4; ++r) {
        float vl = oacc[qh][db][r] / l_run[qh][r];
        int rg = q0 + w * 32 + qh * 16 + (l >> 4) * 4 + r;
        int cg = h * 64 + db * 16 + (l & 15);
        o[(size_t)rg * DIMN + cg] = f2bf(vl);
      }
}

extern "C" void kernel_launch(void* const* d_in, const int* in_sizes, int n_in,
                              void* d_out, int out_size, void* d_ws, size_t ws_size,
                              hipStream_t stream) {
  const float* x  = (const float*)d_in[0];
  const float* wq = (const float*)d_in[1];
  const float* wk = (const float*)d_in[2];
  const float* wv = (const float*)d_in[3];
  const float* wo = (const float*)d_in[4];

  char* ws = (char*)d_ws;
  const size_t MB16 = (size_t)16 * 1024 * 1024;
  const size_t WT_BYTES = (size_t)DIMN * DIMN * 2;  // 128 MB

  const size_t NEED_FUSED = 4 * MB16 + 2 * WT_BYTES;  // 320 MB (ab aliases xb)
  const size_t NEED_DMA   = 5 * MB16 + WT_BYTES;      // 208 MB

  if (ws_size >= NEED_FUSED) {
    // co-scheduled path: transpose(next W) hides under compute-bound GEMM
    unsigned short* xb  = (unsigned short*)(ws);            // also used as ab
    unsigned short* qb  = (unsigned short*)(ws + 1 * MB16);
    unsigned short* kb  = (unsigned short*)(ws + 2 * MB16);
    unsigned short* vb  = (unsigned short*)(ws + 3 * MB16);
    unsigned short* Wt0 = (unsigned short*)(ws + 4 * MB16);
    unsigned short* Wt1 = (unsigned short*)(ws + 4 * MB16 + WT_BYTES);
    unsigned short* ab  = xb;  // xb dead after G(wv); attn writes ab afterward

    cvtT_kernel<<<4096 + 16384, 256, 32768, stream>>>(x, xb, wq, Wt0);
    gemmT_kernel<0><<<512 + 16384, 256, 32768, stream>>>(xb, Wt0, qb, 0.125f, wk, Wt1);
    gemmT_kernel<0><<<512 + 16384, 256, 32768, stream>>>(xb, Wt1, kb, 1.0f, wv, Wt0);
    gemmT_kernel<0><<<512 + 16384, 256, 32768, stream>>>(xb, Wt0, vb, 1.0f, wo, Wt1);
    attn_kernel<<<1024, 256, 0, stream>>>(qb, kb, vb, ab);
    gemmT_kernel<1><<<512, 256, 32768, stream>>>(ab, Wt1, d_out, 1.0f, nullptr, nullptr);
  } else if (ws_size >= NEED_DMA) {
    // serial path (R14/R16 verified: 1060us)
    unsigned short* xb = (unsigned short*)(ws);
    unsigned short* qb = (unsigned short*)(ws + 1 * MB16);
    unsigned short* kb = (unsigned short*)(ws + 2 * MB16);
    unsigned short* vb = (unsigned short*)(ws + 3 * MB16);
    unsigned short* ab = (unsigned short*)(ws + 4 * MB16);
    unsigned short* Wt = (unsigned short*)(ws + 5 * MB16);

    cvt_bf16_kernel<<<4096, 256, 0, stream>>>(x, xb);
    transpose_cvt_kernel<<<16384, 256, 0, stream>>>(wq, Wt);
    gemm_dma<0><<<512, 256, 0, stream>>>(xb, Wt, qb, 0.125f);
    transpose_cvt_kernel<<<16384, 256, 0, stream>>>(wk, Wt);
    gemm_dma<0><<<512, 256, 0, stream>>>(xb, Wt, kb, 1.0f);
    transpose_cvt_kernel<<<16384, 256, 0, stream>>>(wv, Wt);
    gemm_dma<0><<<512, 256, 0, stream>>>(xb, Wt, vb, 1.0f);
    attn_kernel<<<1024, 256, 0, stream>>>(qb, kb, vb, ab);
    transpose_cvt_kernel<<<16384, 256, 0, stream>>>(wo, Wt);
    gemm_dma<1><<<512, 256, 0, stream>>>(ab, Wt, d_out, 1.0f);
  } else {
    unsigned short* xb = (unsigned short*)(ws);
    unsigned short* qb = (unsigned short*)(ws + 1 * MB16);
    unsigned short* kb = (unsigned short*)(ws + 2 * MB16);
    unsigned short* vb = (unsigned short*)(ws + 3 * MB16);
    unsigned short* ab = (unsigned short*)(ws + 4 * MB16);
    cvt_bf16_kernel<<<4096, 256, 0, stream>>>(x, xb);
    gemm_fb<0><<<512, 256, 0, stream>>>(xb, wq, qb, 0.125f);
    gemm_fb<0><<<512, 256, 0, stream>>>(xb, wk, kb, 1.0f);
    gemm_fb<0><<<512, 256, 0, stream>>>(xb, wv, vb, 1.0f);
    attn_kernel<<<1024, 256, 0, stream>>>(qb, kb, vb, ab);
    gemm_fb<1><<<512, 256, 0, stream>>>(ab, wo, d_out, 1.0f);
  }
}